// Round 22
// baseline (91.930 us; speedup 1.0000x reference)
//
#include <hip/hip_runtime.h>
#include <hip/hip_fp16.h>

#define NN 50000
#define EE 1600000
#define CC 128
#define HH 8
#define TOT (EE + NN)               // 1,650,000 output rows
#define RPB 64                      // rows per bucket
#define NB  ((NN + RPB - 1) / RPB)  // 782 buckets
#define CAP 2560                    // fixed slots per bucket (mean 2048, +11 sigma)
#define BCH 4096                    // edges per binning block
#define NBB ((EE + BCH - 1) / BCH)  // 391 binning blocks
#define NPPB 128                    // nodes projected per fused block (391*128 >= NN)
#define EPT (BCH / 1024)            // 4 edges per thread in bin phase
#define NIT 8                       // cached iterations (tot<=64 typical)
#define GRIDF 6144                  // k_final grid-stride blocks
#define SRT 512                     // k_sortrow block size (8 waves)
#define PREG 5                      // per-thread staged payload entries (CAP/SRT)
#define UF 4                        // k_final unroll depth (best measured)

typedef unsigned long long ull;

// leaky_relu(z,0.2)*100
__device__ inline float act(float z) {
    z = (z >= 0.f) ? z : 0.2f * z;
    return z * 100.f;
}

// ---- fused: edge binning (phase 1) + node projection (phase 2) ----
// bin: register-staged rowp, fixed-capacity bucket regions, 2-barrier scan,
//      oidx echo. proj: ykh[r]=interleaved half [y1b,K,...], y2h half.
__global__ __launch_bounds__(1024) void k_projbin(const int* __restrict__ rowp,
                                                  const int* __restrict__ colp,
                                                  const float* __restrict__ ea,
                                                  int* __restrict__ gcur0,
                                                  uint2* __restrict__ pay,
                                                  float* __restrict__ oidx,
                                                  const float* __restrict__ x,
                                                  const float* __restrict__ W,
                                                  const float* __restrict__ bias,
                                                  __half* __restrict__ ykh,
                                                  __half* __restrict__ y2h) {
    __shared__ int hist[NB];
    __shared__ int lscan[NB];
    __shared__ int lofs[NB];
    __shared__ int gofs[NB];
    __shared__ int wsum[16];
    __shared__ uint2 stage[BCH];   // 32 KB (reused as nothing in phase 2)
    __shared__ float w[2 * CC * HH];  // 8 KB, used only in phase 2
    int t = threadIdx.x;
    int lane = t & 63, wv = t >> 6;
    int base = blockIdx.x * BCH;
    int n = EE - base; if (n > BCH) n = BCH;
    for (int i = t; i < NB; i += 1024) hist[i] = 0;
    __syncthreads();
    // register-stage rowp + histogram (single rowp read)
    int rv[EPT];
#pragma unroll
    for (int k = 0; k < EPT; ++k) {
        int i = t + k * 1024;
        rv[k] = -1;
        if (i < n) {
            rv[k] = rowp[base + i];
            atomicAdd(&hist[rv[k] >> 6], 1);
        }
    }
    __syncthreads();
    // hierarchical scan: wave shfl scan + 16 wave partials (2 barriers)
    int own = (t < NB) ? hist[t] : 0;
    int s = own;
#pragma unroll
    for (int off = 1; off < 64; off <<= 1) {
        int u = __shfl_up(s, off, 64);
        if (lane >= off) s += u;
    }
    if (lane == 63) wsum[wv] = s;
    __syncthreads();
    if (t < 16) {
        int v = wsum[t];
        int ss = v;
#pragma unroll
        for (int off = 1; off < 16; off <<= 1) {
            int u = __shfl_up(ss, off, 16);
            if (t >= off) ss += u;
        }
        wsum[t] = ss - v;   // exclusive prefix of wave sums
    }
    __syncthreads();
    int ex = s + wsum[wv] - own;   // exclusive scan over block
    if (t < NB) {
        lscan[t] = ex;
        lofs[t] = ex;
        gofs[t] = own ? (t * CAP + atomicAdd(&gcur0[t], own)) : 0;
    }
    __syncthreads();
    // place packed payload into stage; emit oidx echo (coalesced)
#pragma unroll
    for (int k = 0; k < EPT; ++k) {
        int i = t + k * 1024;
        if (i < n) {
            int e = base + i;
            int r = rv[k];
            int c = colp[e];
            float wgt = fabsf(ea[e]);
            int bkt = r >> 6;
            int p = atomicAdd(&lofs[bkt], 1);
            stage[p] = make_uint2((unsigned)(r & 63) | ((unsigned)c << 6) |
                                  ((unsigned)bkt << 22),
                                  __float_as_uint(wgt));
            __builtin_nontemporal_store((float)r, &oidx[e]);
            __builtin_nontemporal_store((float)c, &oidx[(size_t)TOT + e]);
        }
    }
    __syncthreads();
    // flush: consecutive staged slots of a bucket -> consecutive global slots
    for (int i = t; i < n; i += 1024) {
        uint2 v = stage[i];
        int bkt = v.x >> 22;
        int idx = gofs[bkt] + (i - lscan[bkt]);
        if (idx < (bkt + 1) * CAP)          // overflow guard (p ~ 1e-26)
            pay[idx] = v;
    }
    // ---------------- phase 2: projection of NPPB nodes ----------------
    __syncthreads();
    for (int i = t; i < 2 * CC * HH; i += 1024) w[i] = W[i];
    __syncthreads();
#pragma unroll
    for (int pass = 0; pass < NPPB / 64; ++pass) {
        int node = blockIdx.x * NPPB + pass * 64 + (t >> 4);
        int j = t & 15;
        if (node < NN) {
            int wofs = (j < 8) ? j : (CC * HH + j - 8);
            const float4* xv = (const float4*)(x + (size_t)node * CC);
            float acc = 0.f;
#pragma unroll 4
            for (int k4 = 0; k4 < CC / 4; ++k4) {
                float4 xx = xv[k4];
                int bb = k4 * 32 + wofs;
                acc += xx.x * w[bb];
                acc += xx.y * w[bb + 8];
                acc += xx.z * w[bb + 16];
                acc += xx.w * w[bb + 24];
            }
            if (j < 8) ykh[(size_t)node * 16 + 2 * j] = __float2half(acc + bias[j]);
            else       y2h[(size_t)node * 8 + (j - 8)] = __float2half(acc);
        }
    }
}

// ---- fused: register-staged counting sort (1 global read) + row stats ----
// writes K into ykh (interleaved half), and the self-loop output rows
__global__ __launch_bounds__(SRT) void k_sortrow(const int* __restrict__ gcur0,
                                                 const uint2* __restrict__ pay,
                                                 __half* __restrict__ ykh,
                                                 const __half* __restrict__ y2h,
                                                 float* __restrict__ alpha,
                                                 float* __restrict__ oidx) {
    __shared__ int cnt[RPB];
    __shared__ int rstartL[RPB + 1];
    __shared__ int ofs2[RPB];
    __shared__ uint2 stg[CAP];   // 20.5 KB
    int b = blockIdx.x;
    int t = threadIdx.x;
    int s0 = b * CAP;
    int n = gcur0[b];
    if (n > CAP) n = CAP;
    if (t < RPB) cnt[t] = 0;
    __syncthreads();
    // single coalesced global read into registers + histogram
    uint2 preg[PREG];
#pragma unroll
    for (int k = 0; k < PREG; ++k) {
        int i = t + k * SRT;
        preg[k] = make_uint2(0u, 0u);
        if (i < n) {
            preg[k] = pay[s0 + i];
            atomicAdd(&cnt[preg[k].x & 63], 1);
        }
    }
    __syncthreads();
    if (t < RPB) {
        int v = cnt[t];
        int s = v;
        for (int off = 1; off < 64; off <<= 1) {
            int u = __shfl_up(s, off, 64);
            if (t >= off) s += u;
        }
        int ex = s - v;               // exclusive
        ofs2[t] = ex;
        rstartL[t] = ex;
        if (t == RPB - 1) rstartL[RPB] = s;   // == n
    }
    __syncthreads();
    // scatter from registers into row-sorted LDS
#pragma unroll
    for (int k = 0; k < PREG; ++k) {
        int i = t + k * SRT;
        if (i < n) {
            uint2 p = preg[k];
            int rl = p.x & 63;
            int pos = atomicAdd(&ofs2[rl], 1);
            stg[pos] = make_uint2((p.x >> 6) & 0xFFFF, p.y);
        }
    }
    __syncthreads();
    // row phase: 8 waves x 8 rows each, edges read from LDS
    int wv = t >> 6;
    int lane = t & 63;
    int sub = lane >> 3;   // edge slot within chunk (0..7)
    int h = lane & 7;      // head
    int r0 = b * RPB;
    for (int q = 0; q < 8; ++q) {
        int rr = wv * 8 + q;
        int r = r0 + rr;
        if (r >= NN) break;
        int ls = rstartL[rr];
        int ldeg = rstartL[rr + 1] - ls;
        int tot = ldeg + 1;     // + self loop at slot == ldeg
        float yh = __half2float(ykh[(size_t)r * 16 + 2 * h]);
        float y2s = __half2float(y2h[(size_t)r * 8 + h]);
        float cache[NIT];
        float mx = -__builtin_inff();
#pragma unroll
        for (int it = 0; it < NIT; ++it) {
            int i = it * 8 + sub;
            float a = -__builtin_inff();
            if (i < tot) {
                if (i < ldeg) {
                    uint2 p = stg[ls + i];
                    a = act((yh + __half2float(y2h[(size_t)p.x * 8 + h])) *
                            __uint_as_float(p.y));
                } else {
                    a = act(yh + y2s);
                }
            }
            cache[it] = a;
            mx = fmaxf(mx, a);
        }
        for (int i = NIT * 8 + sub; i < tot; i += 8) {
            float a;
            if (i < ldeg) {
                uint2 p = stg[ls + i];
                a = act((yh + __half2float(y2h[(size_t)p.x * 8 + h])) *
                        __uint_as_float(p.y));
            } else {
                a = act(yh + y2s);
            }
            mx = fmaxf(mx, a);
        }
        mx = fmaxf(mx, __shfl_xor(mx, 8, 64));
        mx = fmaxf(mx, __shfl_xor(mx, 16, 64));
        mx = fmaxf(mx, __shfl_xor(mx, 32, 64));
        float sum = 0.f;
#pragma unroll
        for (int it = 0; it < NIT; ++it)
            sum += __expf(cache[it] - mx);   // exp(-inf)=0 for empty slots
        for (int i = NIT * 8 + sub; i < tot; i += 8) {
            float a;
            if (i < ldeg) {
                uint2 p = stg[ls + i];
                a = act((yh + __half2float(y2h[(size_t)p.x * 8 + h])) *
                        __uint_as_float(p.y));
            } else {
                a = act(yh + y2s);
            }
            sum += __expf(a - mx);
        }
        sum += __shfl_xor(sum, 8, 64);
        sum += __shfl_xor(sum, 16, 64);
        sum += __shfl_xor(sum, 32, 64);
        if (sub == 0) {
            float K = mx + __logf(sum + 1e-16f);
            ykh[(size_t)r * 16 + 2 * h + 1] = __float2half(K);
            float Kr = __half2float(__float2half(K));  // use rounded K everywhere
            // self-loop output row e = EE + r
            float os = __expf(act(yh + y2s) - Kr);
            __builtin_nontemporal_store(os, &alpha[(size_t)(EE + r) * 8 + h]);
            if (h == 0) __builtin_nontemporal_store((float)r, &oidx[EE + r]);
            if (h == 1)
                __builtin_nontemporal_store((float)r, &oidx[(size_t)TOT + EE + r]);
        }
    }
}

// ---- finalize (e < EE only): 2 heads/thread, grid-stride, 4-edge pipeline ----
__global__ __launch_bounds__(256) void k_final(const int* __restrict__ rowp,
                                               const int* __restrict__ colp,
                                               const float* __restrict__ ea,
                                               const __half* __restrict__ ykh,
                                               const __half* __restrict__ y2h,
                                               float* __restrict__ alpha) {
    int gid = blockIdx.x * 256 + threadIdx.x;
    int hp = gid & 3;          // head pair (heads 2hp, 2hp+1)
    int g0 = gid >> 2;
    const int stride = (GRIDF * 256) >> 2;   // edges per step
    for (int e0 = g0; e0 < EE; e0 += UF * stride) {
        int rr[UF], cc[UF]; float ww[UF]; bool hv[UF];
#pragma unroll
        for (int u = 0; u < UF; ++u) {
            int e = e0 + u * stride;
            hv[u] = e < EE;
            rr[u] = 0; cc[u] = 0; ww[u] = 0.f;
            if (hv[u]) {
                rr[u] = rowp[e];
                cc[u] = colp[e];
                ww[u] = fabsf(ea[e]);
            }
        }
        ull yk2[UF]; unsigned v2[UF];
#pragma unroll
        for (int u = 0; u < UF; ++u) {
            yk2[u] = 0ull; v2[u] = 0u;
            if (hv[u]) {
                yk2[u] = *(const ull*)&ykh[(size_t)rr[u] * 16 + 4 * hp];
                v2[u] = *(const unsigned*)&y2h[(size_t)cc[u] * 8 + 2 * hp];
            }
        }
#pragma unroll
        for (int u = 0; u < UF; ++u) {
            if (hv[u]) {
                int e = e0 + u * stride;
                unsigned lo = (unsigned)yk2[u];          // y1b_{2hp}, K_{2hp}
                unsigned hi = (unsigned)(yk2[u] >> 32);  // y1b_{2hp+1}, K_{2hp+1}
                __half2 p0 = *(__half2*)&lo;
                __half2 p1 = *(__half2*)&hi;
                __half2 vvh = *(__half2*)&v2[u];
                float2 f0 = __half22float2(p0);
                float2 f1 = __half22float2(p1);
                float2 vv = __half22float2(vvh);
                float o0 = __expf(act((f0.x + vv.x) * ww[u]) - f0.y);
                float o1 = __expf(act((f1.x + vv.y) * ww[u]) - f1.y);
                ull packed = ((ull)__float_as_uint(o1) << 32) | __float_as_uint(o0);
                __builtin_nontemporal_store(packed,
                    (ull*)&alpha[(size_t)e * 8 + 2 * hp]);
            }
        }
    }
}

extern "C" void kernel_launch(void* const* d_in, const int* in_sizes, int n_in,
                              void* d_out, int out_size, void* d_ws, size_t ws_size,
                              hipStream_t stream) {
    const float* x    = (const float*)d_in[0];
    const int*   rowp = (const int*)d_in[1];          // edge_index[0]
    const int*   colp = rowp + EE;                    // edge_index[1]
    const float* ea   = (const float*)d_in[2];
    const float* W    = (const float*)d_in[3];
    const float* bias = (const float*)d_in[4];

    float* out_alpha = (float*)d_out;                 // [TOT][8]
    float* out_idx   = out_alpha + (size_t)TOT * 8;   // [2][TOT] as float

    // workspace layout
    __half* ykh    = (__half*)d_ws;                   // NN*16 half (y1b|K), 32B/row
    __half* y2h    = ykh + (size_t)NN * 16;           // NN*8 half, 16B/row
    uint2*  pay    = (uint2*)(y2h + (size_t)NN * 8);  // NB*CAP uint2 (16.0 MB)
    int*    gcur0  = (int*)(pay + (size_t)NB * CAP);  // NB

    hipMemsetAsync(gcur0, 0, NB * sizeof(int), stream);
    k_projbin<<<NBB, 1024, 0, stream>>>(rowp, colp, ea, gcur0, pay, out_idx,
                                        x, W, bias, ykh, y2h);
    k_sortrow<<<NB, SRT, 0, stream>>>(gcur0, pay, ykh, y2h, out_alpha, out_idx);
    k_final<<<GRIDF, 256, 0, stream>>>(rowp, colp, ea, ykh, y2h, out_alpha);
}

// Round 23
// 85.705 us; speedup vs baseline: 1.0726x; 1.0726x over previous
//
#include <hip/hip_runtime.h>
#include <hip/hip_fp16.h>

#define NN 50000
#define EE 1600000
#define CC 128
#define HH 8
#define TOT (EE + NN)               // 1,650,000 output rows
#define RPB 64                      // rows per bucket
#define NB  ((NN + RPB - 1) / RPB)  // 782 buckets
#define CAP 2560                    // fixed slots per bucket (mean 2048, +11 sigma)
#define BCH 4096                    // edges per binning block
#define NBB ((EE + BCH - 1) / BCH)  // 391 binning blocks
#define NIT 8                       // cached iterations (tot<=64 typical)
#define GRIDF 6144                  // k_final grid-stride blocks
#define SRT 512                     // k_sortrow block size (8 waves)
#define PREG 5                      // per-thread staged payload entries (CAP/SRT)
#define UF 4                        // k_final unroll depth (best measured)

typedef unsigned long long ull;

// leaky_relu(z,0.2)*100
__device__ inline float act(float z) {
    z = (z >= 0.f) ? z : 0.2f * z;
    return z * 100.f;
}

// ---- ykh[r] = interleaved half [y1b_0,K_0,...] (32B/row); y2h = half (16B/row)
// block 0 additionally zero-inits gcur0
__global__ __launch_bounds__(256) void k_proj(const float* __restrict__ x,
                                              const float* __restrict__ W,
                                              const float* __restrict__ bias,
                                              __half* __restrict__ ykh,
                                              __half* __restrict__ y2h,
                                              int* __restrict__ gcur0) {
    if (blockIdx.x == 0) {
        for (int i = threadIdx.x; i < NB; i += 256) gcur0[i] = 0;
    }
    __shared__ float w[2 * CC * HH];  // 2048 floats
    int tid = threadIdx.x;
    for (int i = tid; i < 2 * CC * HH; i += 256) w[i] = W[i];
    __syncthreads();
    int node = blockIdx.x * 16 + (tid >> 4);
    int j = tid & 15;
    if (node >= NN) return;
    int wofs = (j < 8) ? j : (CC * HH + j - 8);
    const float4* xv = (const float4*)(x + (size_t)node * CC);
    float acc = 0.f;
#pragma unroll 4
    for (int k4 = 0; k4 < CC / 4; ++k4) {
        float4 xx = xv[k4];
        int base = k4 * 32 + wofs;
        acc += xx.x * w[base];
        acc += xx.y * w[base + 8];
        acc += xx.z * w[base + 16];
        acc += xx.w * w[base + 24];
    }
    if (j < 8) ykh[(size_t)node * 16 + 2 * j] = __float2half(acc + bias[j]);
    else       y2h[(size_t)node * 8 + (j - 8)] = __float2half(acc);
}

// ---- binning: vectorized int4/float4 edge loads (4 consecutive edges/thread);
//      fixed-capacity regions; 2-barrier scan; packed NT oidx echo ----
__global__ __launch_bounds__(1024) void k_bin(const int* __restrict__ rowp,
                                              const int* __restrict__ colp,
                                              const float* __restrict__ ea,
                                              int* __restrict__ gcur0,
                                              uint2* __restrict__ pay,
                                              float* __restrict__ oidx) {
    __shared__ int hist[NB];
    __shared__ int lscan[NB];
    __shared__ int lofs[NB];
    __shared__ int gofs[NB];
    __shared__ int wsum[16];
    __shared__ uint2 stage[BCH];   // 32 KB
    int t = threadIdx.x;
    int lane = t & 63, wv = t >> 6;
    int base = blockIdx.x * BCH;
    int n = EE - base; if (n > BCH) n = BCH;
    for (int i = t; i < NB; i += 1024) hist[i] = 0;
    __syncthreads();
    // vectorized register-stage rowp + histogram (single rowp read)
    int i0 = t * 4;
    int rv[4];
    bool full = (i0 + 3 < n);
    if (full) {
        int4 r4 = *(const int4*)&rowp[base + i0];
        rv[0] = r4.x; rv[1] = r4.y; rv[2] = r4.z; rv[3] = r4.w;
#pragma unroll
        for (int k = 0; k < 4; ++k) atomicAdd(&hist[rv[k] >> 6], 1);
    } else {
#pragma unroll
        for (int k = 0; k < 4; ++k) {
            rv[k] = -1;
            if (i0 + k < n) {
                rv[k] = rowp[base + i0 + k];
                atomicAdd(&hist[rv[k] >> 6], 1);
            }
        }
    }
    __syncthreads();
    // hierarchical scan: wave shfl scan + 16 wave partials (2 barriers)
    int own = (t < NB) ? hist[t] : 0;
    int s = own;
#pragma unroll
    for (int off = 1; off < 64; off <<= 1) {
        int u = __shfl_up(s, off, 64);
        if (lane >= off) s += u;
    }
    if (lane == 63) wsum[wv] = s;
    __syncthreads();
    if (t < 16) {
        int v = wsum[t];
        int ss = v;
#pragma unroll
        for (int off = 1; off < 16; off <<= 1) {
            int u = __shfl_up(ss, off, 16);
            if (t >= off) ss += u;
        }
        wsum[t] = ss - v;   // exclusive prefix of wave sums
    }
    __syncthreads();
    int ex = s + wsum[wv] - own;   // exclusive scan over block
    if (t < NB) {
        lscan[t] = ex;
        lofs[t] = ex;
        gofs[t] = own ? (t * CAP + atomicAdd(&gcur0[t], own)) : 0;
    }
    __syncthreads();
    // place packed payload into stage; emit packed oidx echo
    if (full) {
        int4 c4 = *(const int4*)&colp[base + i0];
        float4 e4 = *(const float4*)&ea[base + i0];
        int cs[4] = {c4.x, c4.y, c4.z, c4.w};
        float ws[4] = {fabsf(e4.x), fabsf(e4.y), fabsf(e4.z), fabsf(e4.w)};
#pragma unroll
        for (int k = 0; k < 4; ++k) {
            int bkt = rv[k] >> 6;
            int p = atomicAdd(&lofs[bkt], 1);
            stage[p] = make_uint2((unsigned)(rv[k] & 63) | ((unsigned)cs[k] << 6) |
                                  ((unsigned)bkt << 22),
                                  __float_as_uint(ws[k]));
        }
        // packed NT stores: 2x8B for rows, 2x8B for cols
        ull r01 = ((ull)__float_as_uint((float)rv[1]) << 32) |
                  __float_as_uint((float)rv[0]);
        ull r23 = ((ull)__float_as_uint((float)rv[3]) << 32) |
                  __float_as_uint((float)rv[2]);
        ull c01 = ((ull)__float_as_uint((float)cs[1]) << 32) |
                  __float_as_uint((float)cs[0]);
        ull c23 = ((ull)__float_as_uint((float)cs[3]) << 32) |
                  __float_as_uint((float)cs[2]);
        __builtin_nontemporal_store(r01, (ull*)&oidx[base + i0]);
        __builtin_nontemporal_store(r23, (ull*)&oidx[base + i0 + 2]);
        __builtin_nontemporal_store(c01, (ull*)&oidx[(size_t)TOT + base + i0]);
        __builtin_nontemporal_store(c23, (ull*)&oidx[(size_t)TOT + base + i0 + 2]);
    } else {
#pragma unroll
        for (int k = 0; k < 4; ++k) {
            int i = i0 + k;
            if (i < n) {
                int e = base + i;
                int c = colp[e];
                float wgt = fabsf(ea[e]);
                int bkt = rv[k] >> 6;
                int p = atomicAdd(&lofs[bkt], 1);
                stage[p] = make_uint2((unsigned)(rv[k] & 63) |
                                      ((unsigned)c << 6) |
                                      ((unsigned)bkt << 22),
                                      __float_as_uint(wgt));
                __builtin_nontemporal_store((float)rv[k], &oidx[e]);
                __builtin_nontemporal_store((float)c, &oidx[(size_t)TOT + e]);
            }
        }
    }
    __syncthreads();
    // flush: consecutive staged slots of a bucket -> consecutive global slots
    for (int i = t; i < n; i += 1024) {
        uint2 v = stage[i];
        int bkt = v.x >> 22;
        int idx = gofs[bkt] + (i - lscan[bkt]);
        if (idx < (bkt + 1) * CAP)          // overflow guard (p ~ 1e-26)
            pay[idx] = v;
    }
}

// ---- fused: register-staged counting sort (1 global read) + row stats ----
// writes K into ykh (interleaved half), and the self-loop output rows
__global__ __launch_bounds__(SRT) void k_sortrow(const int* __restrict__ gcur0,
                                                 const uint2* __restrict__ pay,
                                                 __half* __restrict__ ykh,
                                                 const __half* __restrict__ y2h,
                                                 float* __restrict__ alpha,
                                                 float* __restrict__ oidx) {
    __shared__ int cnt[RPB];
    __shared__ int rstartL[RPB + 1];
    __shared__ int ofs2[RPB];
    __shared__ uint2 stg[CAP];   // 20.5 KB
    int b = blockIdx.x;
    int t = threadIdx.x;
    int s0 = b * CAP;
    int n = gcur0[b];
    if (n > CAP) n = CAP;
    if (t < RPB) cnt[t] = 0;
    __syncthreads();
    // single coalesced global read into registers + histogram
    uint2 preg[PREG];
#pragma unroll
    for (int k = 0; k < PREG; ++k) {
        int i = t + k * SRT;
        preg[k] = make_uint2(0u, 0u);
        if (i < n) {
            preg[k] = pay[s0 + i];
            atomicAdd(&cnt[preg[k].x & 63], 1);
        }
    }
    __syncthreads();
    if (t < RPB) {
        int v = cnt[t];
        int s = v;
        for (int off = 1; off < 64; off <<= 1) {
            int u = __shfl_up(s, off, 64);
            if (t >= off) s += u;
        }
        int ex = s - v;               // exclusive
        ofs2[t] = ex;
        rstartL[t] = ex;
        if (t == RPB - 1) rstartL[RPB] = s;   // == n
    }
    __syncthreads();
    // scatter from registers into row-sorted LDS
#pragma unroll
    for (int k = 0; k < PREG; ++k) {
        int i = t + k * SRT;
        if (i < n) {
            uint2 p = preg[k];
            int rl = p.x & 63;
            int pos = atomicAdd(&ofs2[rl], 1);
            stg[pos] = make_uint2((p.x >> 6) & 0xFFFF, p.y);
        }
    }
    __syncthreads();
    // row phase: 8 waves x 8 rows each, edges read from LDS
    int wv = t >> 6;
    int lane = t & 63;
    int sub = lane >> 3;   // edge slot within chunk (0..7)
    int h = lane & 7;      // head
    int r0 = b * RPB;
    for (int q = 0; q < 8; ++q) {
        int rr = wv * 8 + q;
        int r = r0 + rr;
        if (r >= NN) break;
        int ls = rstartL[rr];
        int ldeg = rstartL[rr + 1] - ls;
        int tot = ldeg + 1;     // + self loop at slot == ldeg
        float yh = __half2float(ykh[(size_t)r * 16 + 2 * h]);
        float y2s = __half2float(y2h[(size_t)r * 8 + h]);
        float cache[NIT];
        float mx = -__builtin_inff();
#pragma unroll
        for (int it = 0; it < NIT; ++it) {
            int i = it * 8 + sub;
            float a = -__builtin_inff();
            if (i < tot) {
                if (i < ldeg) {
                    uint2 p = stg[ls + i];
                    a = act((yh + __half2float(y2h[(size_t)p.x * 8 + h])) *
                            __uint_as_float(p.y));
                } else {
                    a = act(yh + y2s);
                }
            }
            cache[it] = a;
            mx = fmaxf(mx, a);
        }
        for (int i = NIT * 8 + sub; i < tot; i += 8) {
            float a;
            if (i < ldeg) {
                uint2 p = stg[ls + i];
                a = act((yh + __half2float(y2h[(size_t)p.x * 8 + h])) *
                        __uint_as_float(p.y));
            } else {
                a = act(yh + y2s);
            }
            mx = fmaxf(mx, a);
        }
        mx = fmaxf(mx, __shfl_xor(mx, 8, 64));
        mx = fmaxf(mx, __shfl_xor(mx, 16, 64));
        mx = fmaxf(mx, __shfl_xor(mx, 32, 64));
        float sum = 0.f;
#pragma unroll
        for (int it = 0; it < NIT; ++it)
            sum += __expf(cache[it] - mx);   // exp(-inf)=0 for empty slots
        for (int i = NIT * 8 + sub; i < tot; i += 8) {
            float a;
            if (i < ldeg) {
                uint2 p = stg[ls + i];
                a = act((yh + __half2float(y2h[(size_t)p.x * 8 + h])) *
                        __uint_as_float(p.y));
            } else {
                a = act(yh + y2s);
            }
            sum += __expf(a - mx);
        }
        sum += __shfl_xor(sum, 8, 64);
        sum += __shfl_xor(sum, 16, 64);
        sum += __shfl_xor(sum, 32, 64);
        if (sub == 0) {
            float K = mx + __logf(sum + 1e-16f);
            ykh[(size_t)r * 16 + 2 * h + 1] = __float2half(K);
            float Kr = __half2float(__float2half(K));  // use rounded K everywhere
            // self-loop output row e = EE + r
            float os = __expf(act(yh + y2s) - Kr);
            __builtin_nontemporal_store(os, &alpha[(size_t)(EE + r) * 8 + h]);
            if (h == 0) __builtin_nontemporal_store((float)r, &oidx[EE + r]);
            if (h == 1)
                __builtin_nontemporal_store((float)r, &oidx[(size_t)TOT + EE + r]);
        }
    }
}

// ---- finalize (e < EE only): 2 heads/thread, grid-stride, 4-edge pipeline ----
__global__ __launch_bounds__(256) void k_final(const int* __restrict__ rowp,
                                               const int* __restrict__ colp,
                                               const float* __restrict__ ea,
                                               const __half* __restrict__ ykh,
                                               const __half* __restrict__ y2h,
                                               float* __restrict__ alpha) {
    int gid = blockIdx.x * 256 + threadIdx.x;
    int hp = gid & 3;          // head pair (heads 2hp, 2hp+1)
    int g0 = gid >> 2;
    const int stride = (GRIDF * 256) >> 2;   // edges per step
    for (int e0 = g0; e0 < EE; e0 += UF * stride) {
        int rr[UF], cc[UF]; float ww[UF]; bool hv[UF];
#pragma unroll
        for (int u = 0; u < UF; ++u) {
            int e = e0 + u * stride;
            hv[u] = e < EE;
            rr[u] = 0; cc[u] = 0; ww[u] = 0.f;
            if (hv[u]) {
                rr[u] = rowp[e];
                cc[u] = colp[e];
                ww[u] = fabsf(ea[e]);
            }
        }
        ull yk2[UF]; unsigned v2[UF];
#pragma unroll
        for (int u = 0; u < UF; ++u) {
            yk2[u] = 0ull; v2[u] = 0u;
            if (hv[u]) {
                yk2[u] = *(const ull*)&ykh[(size_t)rr[u] * 16 + 4 * hp];
                v2[u] = *(const unsigned*)&y2h[(size_t)cc[u] * 8 + 2 * hp];
            }
        }
#pragma unroll
        for (int u = 0; u < UF; ++u) {
            if (hv[u]) {
                int e = e0 + u * stride;
                unsigned lo = (unsigned)yk2[u];          // y1b_{2hp}, K_{2hp}
                unsigned hi = (unsigned)(yk2[u] >> 32);  // y1b_{2hp+1}, K_{2hp+1}
                __half2 p0 = *(__half2*)&lo;
                __half2 p1 = *(__half2*)&hi;
                __half2 vvh = *(__half2*)&v2[u];
                float2 f0 = __half22float2(p0);
                float2 f1 = __half22float2(p1);
                float2 vv = __half22float2(vvh);
                float o0 = __expf(act((f0.x + vv.x) * ww[u]) - f0.y);
                float o1 = __expf(act((f1.x + vv.y) * ww[u]) - f1.y);
                ull packed = ((ull)__float_as_uint(o1) << 32) | __float_as_uint(o0);
                __builtin_nontemporal_store(packed,
                    (ull*)&alpha[(size_t)e * 8 + 2 * hp]);
            }
        }
    }
}

extern "C" void kernel_launch(void* const* d_in, const int* in_sizes, int n_in,
                              void* d_out, int out_size, void* d_ws, size_t ws_size,
                              hipStream_t stream) {
    const float* x    = (const float*)d_in[0];
    const int*   rowp = (const int*)d_in[1];          // edge_index[0]
    const int*   colp = rowp + EE;                    // edge_index[1]
    const float* ea   = (const float*)d_in[2];
    const float* W    = (const float*)d_in[3];
    const float* bias = (const float*)d_in[4];

    float* out_alpha = (float*)d_out;                 // [TOT][8]
    float* out_idx   = out_alpha + (size_t)TOT * 8;   // [2][TOT] as float

    // workspace layout
    __half* ykh    = (__half*)d_ws;                   // NN*16 half (y1b|K), 32B/row
    __half* y2h    = ykh + (size_t)NN * 16;           // NN*8 half, 16B/row
    uint2*  pay    = (uint2*)(y2h + (size_t)NN * 8);  // NB*CAP uint2 (16.0 MB)
    int*    gcur0  = (int*)(pay + (size_t)NB * CAP);  // NB (zeroed by k_proj)

    k_proj<<<(NN * 16 + 255) / 256, 256, 0, stream>>>(x, W, bias, ykh, y2h, gcur0);
    k_bin<<<NBB, 1024, 0, stream>>>(rowp, colp, ea, gcur0, pay, out_idx);
    k_sortrow<<<NB, SRT, 0, stream>>>(gcur0, pay, ykh, y2h, out_alpha, out_idx);
    k_final<<<GRIDF, 256, 0, stream>>>(rowp, colp, ea, ykh, y2h, out_alpha);
}

// Round 24
// 85.454 us; speedup vs baseline: 1.0758x; 1.0029x over previous
//
#include <hip/hip_runtime.h>
#include <hip/hip_fp16.h>

#define NN 50000
#define EE 1600000
#define CC 128
#define HH 8
#define TOT (EE + NN)               // 1,650,000 output rows
#define RPB 64                      // rows per bucket
#define NB  ((NN + RPB - 1) / RPB)  // 782 buckets
#define CAP 2560                    // fixed slots per bucket (mean 2048, +11 sigma)
#define BCH 4096                    // edges per binning block
#define NBB ((EE + BCH - 1) / BCH)  // 391 binning blocks
#define NIT 8                       // cached iterations (tot<=64 typical)
#define GRIDF 6144                  // k_final grid-stride blocks
#define SRT 512                     // k_sortrow block size (8 waves)
#define PREG 5                      // per-thread staged payload entries (CAP/SRT)
#define UF 4                        // k_final unroll depth (best measured)

typedef unsigned long long ull;

// leaky_relu(z,0.2)*100
__device__ inline float act(float z) {
    z = (z >= 0.f) ? z : 0.2f * z;
    return z * 100.f;
}

// ---- ykh[r] = interleaved half [y1b_0,K_0,...] (32B/row); y2h = half (16B/row)
// block 0 additionally zero-inits gcur0
__global__ __launch_bounds__(256) void k_proj(const float* __restrict__ x,
                                              const float* __restrict__ W,
                                              const float* __restrict__ bias,
                                              __half* __restrict__ ykh,
                                              __half* __restrict__ y2h,
                                              int* __restrict__ gcur0) {
    if (blockIdx.x == 0) {
        for (int i = threadIdx.x; i < NB; i += 256) gcur0[i] = 0;
    }
    __shared__ float w[2 * CC * HH];  // 2048 floats
    int tid = threadIdx.x;
    for (int i = tid; i < 2 * CC * HH; i += 256) w[i] = W[i];
    __syncthreads();
    int node = blockIdx.x * 16 + (tid >> 4);
    int j = tid & 15;
    if (node >= NN) return;
    int wofs = (j < 8) ? j : (CC * HH + j - 8);
    const float4* xv = (const float4*)(x + (size_t)node * CC);
    float acc = 0.f;
#pragma unroll 4
    for (int k4 = 0; k4 < CC / 4; ++k4) {
        float4 xx = xv[k4];
        int base = k4 * 32 + wofs;
        acc += xx.x * w[base];
        acc += xx.y * w[base + 8];
        acc += xx.z * w[base + 16];
        acc += xx.w * w[base + 24];
    }
    if (j < 8) ykh[(size_t)node * 16 + 2 * j] = __float2half(acc + bias[j]);
    else       y2h[(size_t)node * 8 + (j - 8)] = __float2half(acc);
}

// ---- binning: vectorized int4/float4 edge loads (4 consecutive edges/thread);
//      fixed-capacity regions; 2-barrier scan; packed NT oidx echo ----
__global__ __launch_bounds__(1024) void k_bin(const int* __restrict__ rowp,
                                              const int* __restrict__ colp,
                                              const float* __restrict__ ea,
                                              int* __restrict__ gcur0,
                                              uint2* __restrict__ pay,
                                              float* __restrict__ oidx) {
    __shared__ int hist[NB];
    __shared__ int lscan[NB];
    __shared__ int lofs[NB];
    __shared__ int gofs[NB];
    __shared__ int wsum[16];
    __shared__ uint2 stage[BCH];   // 32 KB
    int t = threadIdx.x;
    int lane = t & 63, wv = t >> 6;
    int base = blockIdx.x * BCH;
    int n = EE - base; if (n > BCH) n = BCH;
    for (int i = t; i < NB; i += 1024) hist[i] = 0;
    __syncthreads();
    // vectorized register-stage rowp + histogram (single rowp read)
    int i0 = t * 4;
    int rv[4];
    bool full = (i0 + 3 < n);
    if (full) {
        int4 r4 = *(const int4*)&rowp[base + i0];
        rv[0] = r4.x; rv[1] = r4.y; rv[2] = r4.z; rv[3] = r4.w;
#pragma unroll
        for (int k = 0; k < 4; ++k) atomicAdd(&hist[rv[k] >> 6], 1);
    } else {
#pragma unroll
        for (int k = 0; k < 4; ++k) {
            rv[k] = -1;
            if (i0 + k < n) {
                rv[k] = rowp[base + i0 + k];
                atomicAdd(&hist[rv[k] >> 6], 1);
            }
        }
    }
    __syncthreads();
    // hierarchical scan: wave shfl scan + 16 wave partials (2 barriers)
    int own = (t < NB) ? hist[t] : 0;
    int s = own;
#pragma unroll
    for (int off = 1; off < 64; off <<= 1) {
        int u = __shfl_up(s, off, 64);
        if (lane >= off) s += u;
    }
    if (lane == 63) wsum[wv] = s;
    __syncthreads();
    if (t < 16) {
        int v = wsum[t];
        int ss = v;
#pragma unroll
        for (int off = 1; off < 16; off <<= 1) {
            int u = __shfl_up(ss, off, 16);
            if (t >= off) ss += u;
        }
        wsum[t] = ss - v;   // exclusive prefix of wave sums
    }
    __syncthreads();
    int ex = s + wsum[wv] - own;   // exclusive scan over block
    if (t < NB) {
        lscan[t] = ex;
        lofs[t] = ex;
        gofs[t] = own ? (t * CAP + atomicAdd(&gcur0[t], own)) : 0;
    }
    __syncthreads();
    // place packed payload into stage; emit packed oidx echo
    if (full) {
        int4 c4 = *(const int4*)&colp[base + i0];
        float4 e4 = *(const float4*)&ea[base + i0];
        int cs[4] = {c4.x, c4.y, c4.z, c4.w};
        float ws[4] = {fabsf(e4.x), fabsf(e4.y), fabsf(e4.z), fabsf(e4.w)};
#pragma unroll
        for (int k = 0; k < 4; ++k) {
            int bkt = rv[k] >> 6;
            int p = atomicAdd(&lofs[bkt], 1);
            stage[p] = make_uint2((unsigned)(rv[k] & 63) | ((unsigned)cs[k] << 6) |
                                  ((unsigned)bkt << 22),
                                  __float_as_uint(ws[k]));
        }
        // packed NT stores: 2x8B for rows, 2x8B for cols
        ull r01 = ((ull)__float_as_uint((float)rv[1]) << 32) |
                  __float_as_uint((float)rv[0]);
        ull r23 = ((ull)__float_as_uint((float)rv[3]) << 32) |
                  __float_as_uint((float)rv[2]);
        ull c01 = ((ull)__float_as_uint((float)cs[1]) << 32) |
                  __float_as_uint((float)cs[0]);
        ull c23 = ((ull)__float_as_uint((float)cs[3]) << 32) |
                  __float_as_uint((float)cs[2]);
        __builtin_nontemporal_store(r01, (ull*)&oidx[base + i0]);
        __builtin_nontemporal_store(r23, (ull*)&oidx[base + i0 + 2]);
        __builtin_nontemporal_store(c01, (ull*)&oidx[(size_t)TOT + base + i0]);
        __builtin_nontemporal_store(c23, (ull*)&oidx[(size_t)TOT + base + i0 + 2]);
    } else {
#pragma unroll
        for (int k = 0; k < 4; ++k) {
            int i = i0 + k;
            if (i < n) {
                int e = base + i;
                int c = colp[e];
                float wgt = fabsf(ea[e]);
                int bkt = rv[k] >> 6;
                int p = atomicAdd(&lofs[bkt], 1);
                stage[p] = make_uint2((unsigned)(rv[k] & 63) |
                                      ((unsigned)c << 6) |
                                      ((unsigned)bkt << 22),
                                      __float_as_uint(wgt));
                __builtin_nontemporal_store((float)rv[k], &oidx[e]);
                __builtin_nontemporal_store((float)c, &oidx[(size_t)TOT + e]);
            }
        }
    }
    __syncthreads();
    // flush: consecutive staged slots of a bucket -> consecutive global slots
    for (int i = t; i < n; i += 1024) {
        uint2 v = stage[i];
        int bkt = v.x >> 22;
        int idx = gofs[bkt] + (i - lscan[bkt]);
        if (idx < (bkt + 1) * CAP)          // overflow guard (p ~ 1e-26)
            pay[idx] = v;
    }
}

// ---- fused: register-staged counting sort (1 global read) + row stats ----
// writes K into ykh (interleaved half), and the self-loop output rows
__global__ __launch_bounds__(SRT) void k_sortrow(const int* __restrict__ gcur0,
                                                 const uint2* __restrict__ pay,
                                                 __half* __restrict__ ykh,
                                                 const __half* __restrict__ y2h,
                                                 float* __restrict__ alpha,
                                                 float* __restrict__ oidx) {
    __shared__ int cnt[RPB];
    __shared__ int rstartL[RPB + 1];
    __shared__ int ofs2[RPB];
    __shared__ uint2 stg[CAP];   // 20.5 KB
    int b = blockIdx.x;
    int t = threadIdx.x;
    int s0 = b * CAP;
    int n = gcur0[b];
    if (n > CAP) n = CAP;
    if (t < RPB) cnt[t] = 0;
    __syncthreads();
    // single coalesced global read into registers + histogram
    uint2 preg[PREG];
#pragma unroll
    for (int k = 0; k < PREG; ++k) {
        int i = t + k * SRT;
        preg[k] = make_uint2(0u, 0u);
        if (i < n) {
            preg[k] = pay[s0 + i];
            atomicAdd(&cnt[preg[k].x & 63], 1);
        }
    }
    __syncthreads();
    if (t < RPB) {
        int v = cnt[t];
        int s = v;
        for (int off = 1; off < 64; off <<= 1) {
            int u = __shfl_up(s, off, 64);
            if (t >= off) s += u;
        }
        int ex = s - v;               // exclusive
        ofs2[t] = ex;
        rstartL[t] = ex;
        if (t == RPB - 1) rstartL[RPB] = s;   // == n
    }
    __syncthreads();
    // scatter from registers into row-sorted LDS
#pragma unroll
    for (int k = 0; k < PREG; ++k) {
        int i = t + k * SRT;
        if (i < n) {
            uint2 p = preg[k];
            int rl = p.x & 63;
            int pos = atomicAdd(&ofs2[rl], 1);
            stg[pos] = make_uint2((p.x >> 6) & 0xFFFF, p.y);
        }
    }
    __syncthreads();
    // row phase: 8 waves x 8 rows each; guarded (no break) so the compiler
    // can unroll and interleave independent row chains for ILP
    int wv = t >> 6;
    int lane = t & 63;
    int sub = lane >> 3;   // edge slot within chunk (0..7)
    int h = lane & 7;      // head
    int r0 = b * RPB;
#pragma unroll 2
    for (int q = 0; q < 8; ++q) {
        int rr = wv * 8 + q;
        int r = r0 + rr;
        if (r < NN) {
            int ls = rstartL[rr];
            int ldeg = rstartL[rr + 1] - ls;
            int tot = ldeg + 1;     // + self loop at slot == ldeg
            float yh = __half2float(ykh[(size_t)r * 16 + 2 * h]);
            float y2s = __half2float(y2h[(size_t)r * 8 + h]);
            float cache[NIT];
            float mx = -__builtin_inff();
#pragma unroll
            for (int it = 0; it < NIT; ++it) {
                int i = it * 8 + sub;
                float a = -__builtin_inff();
                if (i < tot) {
                    if (i < ldeg) {
                        uint2 p = stg[ls + i];
                        a = act((yh + __half2float(y2h[(size_t)p.x * 8 + h])) *
                                __uint_as_float(p.y));
                    } else {
                        a = act(yh + y2s);
                    }
                }
                cache[it] = a;
                mx = fmaxf(mx, a);
            }
            for (int i = NIT * 8 + sub; i < tot; i += 8) {
                float a;
                if (i < ldeg) {
                    uint2 p = stg[ls + i];
                    a = act((yh + __half2float(y2h[(size_t)p.x * 8 + h])) *
                            __uint_as_float(p.y));
                } else {
                    a = act(yh + y2s);
                }
                mx = fmaxf(mx, a);
            }
            mx = fmaxf(mx, __shfl_xor(mx, 8, 64));
            mx = fmaxf(mx, __shfl_xor(mx, 16, 64));
            mx = fmaxf(mx, __shfl_xor(mx, 32, 64));
            float sum = 0.f;
#pragma unroll
            for (int it = 0; it < NIT; ++it)
                sum += __expf(cache[it] - mx);   // exp(-inf)=0 for empty slots
            for (int i = NIT * 8 + sub; i < tot; i += 8) {
                float a;
                if (i < ldeg) {
                    uint2 p = stg[ls + i];
                    a = act((yh + __half2float(y2h[(size_t)p.x * 8 + h])) *
                            __uint_as_float(p.y));
                } else {
                    a = act(yh + y2s);
                }
                sum += __expf(a - mx);
            }
            sum += __shfl_xor(sum, 8, 64);
            sum += __shfl_xor(sum, 16, 64);
            sum += __shfl_xor(sum, 32, 64);
            if (sub == 0) {
                float K = mx + __logf(sum + 1e-16f);
                ykh[(size_t)r * 16 + 2 * h + 1] = __float2half(K);
                float Kr = __half2float(__float2half(K));  // rounded K everywhere
                // self-loop output row e = EE + r
                float os = __expf(act(yh + y2s) - Kr);
                __builtin_nontemporal_store(os, &alpha[(size_t)(EE + r) * 8 + h]);
                if (h == 0) __builtin_nontemporal_store((float)r, &oidx[EE + r]);
                if (h == 1)
                    __builtin_nontemporal_store((float)r,
                                                &oidx[(size_t)TOT + EE + r]);
            }
        }
    }
}

// ---- finalize (e < EE only): 2 heads/thread, grid-stride, 4-edge pipeline ----
__global__ __launch_bounds__(256) void k_final(const int* __restrict__ rowp,
                                               const int* __restrict__ colp,
                                               const float* __restrict__ ea,
                                               const __half* __restrict__ ykh,
                                               const __half* __restrict__ y2h,
                                               float* __restrict__ alpha) {
    int gid = blockIdx.x * 256 + threadIdx.x;
    int hp = gid & 3;          // head pair (heads 2hp, 2hp+1)
    int g0 = gid >> 2;
    const int stride = (GRIDF * 256) >> 2;   // edges per step
    for (int e0 = g0; e0 < EE; e0 += UF * stride) {
        int rr[UF], cc[UF]; float ww[UF]; bool hv[UF];
#pragma unroll
        for (int u = 0; u < UF; ++u) {
            int e = e0 + u * stride;
            hv[u] = e < EE;
            rr[u] = 0; cc[u] = 0; ww[u] = 0.f;
            if (hv[u]) {
                rr[u] = rowp[e];
                cc[u] = colp[e];
                ww[u] = fabsf(ea[e]);
            }
        }
        ull yk2[UF]; unsigned v2[UF];
#pragma unroll
        for (int u = 0; u < UF; ++u) {
            yk2[u] = 0ull; v2[u] = 0u;
            if (hv[u]) {
                yk2[u] = *(const ull*)&ykh[(size_t)rr[u] * 16 + 4 * hp];
                v2[u] = *(const unsigned*)&y2h[(size_t)cc[u] * 8 + 2 * hp];
            }
        }
#pragma unroll
        for (int u = 0; u < UF; ++u) {
            if (hv[u]) {
                int e = e0 + u * stride;
                unsigned lo = (unsigned)yk2[u];          // y1b_{2hp}, K_{2hp}
                unsigned hi = (unsigned)(yk2[u] >> 32);  // y1b_{2hp+1}, K_{2hp+1}
                __half2 p0 = *(__half2*)&lo;
                __half2 p1 = *(__half2*)&hi;
                __half2 vvh = *(__half2*)&v2[u];
                float2 f0 = __half22float2(p0);
                float2 f1 = __half22float2(p1);
                float2 vv = __half22float2(vvh);
                float o0 = __expf(act((f0.x + vv.x) * ww[u]) - f0.y);
                float o1 = __expf(act((f1.x + vv.y) * ww[u]) - f1.y);
                ull packed = ((ull)__float_as_uint(o1) << 32) | __float_as_uint(o0);
                __builtin_nontemporal_store(packed,
                    (ull*)&alpha[(size_t)e * 8 + 2 * hp]);
            }
        }
    }
}

extern "C" void kernel_launch(void* const* d_in, const int* in_sizes, int n_in,
                              void* d_out, int out_size, void* d_ws, size_t ws_size,
                              hipStream_t stream) {
    const float* x    = (const float*)d_in[0];
    const int*   rowp = (const int*)d_in[1];          // edge_index[0]
    const int*   colp = rowp + EE;                    // edge_index[1]
    const float* ea   = (const float*)d_in[2];
    const float* W    = (const float*)d_in[3];
    const float* bias = (const float*)d_in[4];

    float* out_alpha = (float*)d_out;                 // [TOT][8]
    float* out_idx   = out_alpha + (size_t)TOT * 8;   // [2][TOT] as float

    // workspace layout
    __half* ykh    = (__half*)d_ws;                   // NN*16 half (y1b|K), 32B/row
    __half* y2h    = ykh + (size_t)NN * 16;           // NN*8 half, 16B/row
    uint2*  pay    = (uint2*)(y2h + (size_t)NN * 8);  // NB*CAP uint2 (16.0 MB)
    int*    gcur0  = (int*)(pay + (size_t)NB * CAP);  // NB (zeroed by k_proj)

    k_proj<<<(NN * 16 + 255) / 256, 256, 0, stream>>>(x, W, bias, ykh, y2h, gcur0);
    k_bin<<<NBB, 1024, 0, stream>>>(rowp, colp, ea, gcur0, pay, out_idx);
    k_sortrow<<<NB, SRT, 0, stream>>>(gcur0, pay, ykh, y2h, out_alpha, out_idx);
    k_final<<<GRIDF, 256, 0, stream>>>(rowp, colp, ea, ykh, y2h, out_alpha);
}

// Round 25
// 85.157 us; speedup vs baseline: 1.0795x; 1.0035x over previous
//
#include <hip/hip_runtime.h>
#include <hip/hip_fp16.h>

#define NN 50000
#define EE 1600000
#define CC 128
#define HH 8
#define TOT (EE + NN)               // 1,650,000 output rows
#define RPB 64                      // rows per bucket
#define NB  ((NN + RPB - 1) / RPB)  // 782 buckets
#define CAP 2560                    // fixed slots per bucket (mean 2048, +11 sigma)
#define BCH 4096                    // edges per binning block
#define NBB ((EE + BCH - 1) / BCH)  // 391 binning blocks
#define NIT 8                       // cached iterations (tot<=64 typical)
#define GRIDF 6400                  // k_final grid-stride blocks (single pass)
#define SRT 512                     // k_sortrow block size (8 waves)
#define UF 4                        // k_final unroll depth (best measured)

typedef unsigned long long ull;

// leaky_relu(z,0.2)*100
__device__ inline float act(float z) {
    z = (z >= 0.f) ? z : 0.2f * z;
    return z * 100.f;
}

// ---- ykh[r] = interleaved half [y1b_0,K_0,...] (32B/row); y2h = half (16B/row)
// block 0 additionally zero-inits gcur0
__global__ __launch_bounds__(256) void k_proj(const float* __restrict__ x,
                                              const float* __restrict__ W,
                                              const float* __restrict__ bias,
                                              __half* __restrict__ ykh,
                                              __half* __restrict__ y2h,
                                              int* __restrict__ gcur0) {
    if (blockIdx.x == 0) {
        for (int i = threadIdx.x; i < NB; i += 256) gcur0[i] = 0;
    }
    __shared__ float w[2 * CC * HH];  // 2048 floats
    int tid = threadIdx.x;
    for (int i = tid; i < 2 * CC * HH; i += 256) w[i] = W[i];
    __syncthreads();
    int node = blockIdx.x * 16 + (tid >> 4);
    int j = tid & 15;
    if (node >= NN) return;
    int wofs = (j < 8) ? j : (CC * HH + j - 8);
    const float4* xv = (const float4*)(x + (size_t)node * CC);
    float acc = 0.f;
#pragma unroll 4
    for (int k4 = 0; k4 < CC / 4; ++k4) {
        float4 xx = xv[k4];
        int base = k4 * 32 + wofs;
        acc += xx.x * w[base];
        acc += xx.y * w[base + 8];
        acc += xx.z * w[base + 16];
        acc += xx.w * w[base + 24];
    }
    if (j < 8) ykh[(size_t)node * 16 + 2 * j] = __float2half(acc + bias[j]);
    else       y2h[(size_t)node * 8 + (j - 8)] = __float2half(acc);
}

// ---- binning: all 3 edge streams loaded up-front (latency hidden under scan);
//      fixed-capacity regions; 2-barrier scan; packed NT oidx echo ----
__global__ __launch_bounds__(1024) void k_bin(const int* __restrict__ rowp,
                                              const int* __restrict__ colp,
                                              const float* __restrict__ ea,
                                              int* __restrict__ gcur0,
                                              uint2* __restrict__ pay,
                                              float* __restrict__ oidx) {
    __shared__ int hist[NB];
    __shared__ int lscan[NB];
    __shared__ int lofs[NB];
    __shared__ int gofs[NB];
    __shared__ int wsum[16];
    __shared__ uint2 stage[BCH];   // 32 KB
    int t = threadIdx.x;
    int lane = t & 63, wv = t >> 6;
    int base = blockIdx.x * BCH;
    int n = EE - base; if (n > BCH) n = BCH;
    for (int i = t; i < NB; i += 1024) hist[i] = 0;
    __syncthreads();
    // vectorized register-stage of ALL edge streams (issued before the scan,
    // so colp/ea latency hides under the scan phase)
    int i0 = t * 4;
    int rv[4], cs[4]; float wsv[4];
    bool full = (i0 + 3 < n);
    if (full) {
        int4 r4 = *(const int4*)&rowp[base + i0];
        int4 c4 = *(const int4*)&colp[base + i0];
        float4 e4 = *(const float4*)&ea[base + i0];
        rv[0] = r4.x; rv[1] = r4.y; rv[2] = r4.z; rv[3] = r4.w;
        cs[0] = c4.x; cs[1] = c4.y; cs[2] = c4.z; cs[3] = c4.w;
        wsv[0] = fabsf(e4.x); wsv[1] = fabsf(e4.y);
        wsv[2] = fabsf(e4.z); wsv[3] = fabsf(e4.w);
#pragma unroll
        for (int k = 0; k < 4; ++k) atomicAdd(&hist[rv[k] >> 6], 1);
    } else {
#pragma unroll
        for (int k = 0; k < 4; ++k) {
            rv[k] = -1; cs[k] = 0; wsv[k] = 0.f;
            if (i0 + k < n) {
                rv[k] = rowp[base + i0 + k];
                cs[k] = colp[base + i0 + k];
                wsv[k] = fabsf(ea[base + i0 + k]);
                atomicAdd(&hist[rv[k] >> 6], 1);
            }
        }
    }
    __syncthreads();
    // hierarchical scan: wave shfl scan + 16 wave partials (2 barriers)
    int own = (t < NB) ? hist[t] : 0;
    int s = own;
#pragma unroll
    for (int off = 1; off < 64; off <<= 1) {
        int u = __shfl_up(s, off, 64);
        if (lane >= off) s += u;
    }
    if (lane == 63) wsum[wv] = s;
    __syncthreads();
    if (t < 16) {
        int v = wsum[t];
        int ss = v;
#pragma unroll
        for (int off = 1; off < 16; off <<= 1) {
            int u = __shfl_up(ss, off, 16);
            if (t >= off) ss += u;
        }
        wsum[t] = ss - v;   // exclusive prefix of wave sums
    }
    __syncthreads();
    int ex = s + wsum[wv] - own;   // exclusive scan over block
    if (t < NB) {
        lscan[t] = ex;
        lofs[t] = ex;
        gofs[t] = own ? (t * CAP + atomicAdd(&gcur0[t], own)) : 0;
    }
    __syncthreads();
    // place packed payload into stage; emit packed oidx echo (all from regs)
    if (full) {
#pragma unroll
        for (int k = 0; k < 4; ++k) {
            int bkt = rv[k] >> 6;
            int p = atomicAdd(&lofs[bkt], 1);
            stage[p] = make_uint2((unsigned)(rv[k] & 63) | ((unsigned)cs[k] << 6) |
                                  ((unsigned)bkt << 22),
                                  __float_as_uint(wsv[k]));
        }
        ull r01 = ((ull)__float_as_uint((float)rv[1]) << 32) |
                  __float_as_uint((float)rv[0]);
        ull r23 = ((ull)__float_as_uint((float)rv[3]) << 32) |
                  __float_as_uint((float)rv[2]);
        ull c01 = ((ull)__float_as_uint((float)cs[1]) << 32) |
                  __float_as_uint((float)cs[0]);
        ull c23 = ((ull)__float_as_uint((float)cs[3]) << 32) |
                  __float_as_uint((float)cs[2]);
        __builtin_nontemporal_store(r01, (ull*)&oidx[base + i0]);
        __builtin_nontemporal_store(r23, (ull*)&oidx[base + i0 + 2]);
        __builtin_nontemporal_store(c01, (ull*)&oidx[(size_t)TOT + base + i0]);
        __builtin_nontemporal_store(c23, (ull*)&oidx[(size_t)TOT + base + i0 + 2]);
    } else {
#pragma unroll
        for (int k = 0; k < 4; ++k) {
            int i = i0 + k;
            if (i < n) {
                int e = base + i;
                int bkt = rv[k] >> 6;
                int p = atomicAdd(&lofs[bkt], 1);
                stage[p] = make_uint2((unsigned)(rv[k] & 63) |
                                      ((unsigned)cs[k] << 6) |
                                      ((unsigned)bkt << 22),
                                      __float_as_uint(wsv[k]));
                __builtin_nontemporal_store((float)rv[k], &oidx[e]);
                __builtin_nontemporal_store((float)cs[k], &oidx[(size_t)TOT + e]);
            }
        }
    }
    __syncthreads();
    // flush: consecutive staged slots of a bucket -> consecutive global slots
    for (int i = t; i < n; i += 1024) {
        uint2 v = stage[i];
        int bkt = v.x >> 22;
        int idx = gofs[bkt] + (i - lscan[bkt]);
        if (idx < (bkt + 1) * CAP)          // overflow guard (p ~ 1e-26)
            pay[idx] = v;
    }
}

// ---- fused: register-staged counting sort (uint4 pay loads) + row stats ----
// writes K into ykh (interleaved half), and the self-loop output rows
__global__ __launch_bounds__(SRT) void k_sortrow(const int* __restrict__ gcur0,
                                                 const uint2* __restrict__ pay,
                                                 __half* __restrict__ ykh,
                                                 const __half* __restrict__ y2h,
                                                 float* __restrict__ alpha,
                                                 float* __restrict__ oidx) {
    __shared__ int cnt[RPB];
    __shared__ int rstartL[RPB + 1];
    __shared__ int ofs2[RPB];
    __shared__ uint2 stg[CAP];   // 20.5 KB
    int b = blockIdx.x;
    int t = threadIdx.x;
    int s0 = b * CAP;
    int n = gcur0[b];
    if (n > CAP) n = CAP;
    if (t < RPB) cnt[t] = 0;
    __syncthreads();
    // paired 16B global reads into registers (entries 2t+k*1024, +1)
    uint2 preg[6];
#pragma unroll
    for (int k = 0; k < 3; ++k) {
        int i = 2 * t + k * 1024;
        preg[2 * k] = make_uint2(0u, 0u);
        preg[2 * k + 1] = make_uint2(0u, 0u);
        if (i + 1 < n) {
            uint4 v = *(const uint4*)&pay[s0 + i];
            preg[2 * k] = make_uint2(v.x, v.y);
            preg[2 * k + 1] = make_uint2(v.z, v.w);
        } else if (i < n) {
            preg[2 * k] = pay[s0 + i];
        }
    }
    // histogram from registers
#pragma unroll
    for (int k = 0; k < 6; ++k) {
        int i = 2 * t + (k >> 1) * 1024 + (k & 1);
        if (i < n) atomicAdd(&cnt[preg[k].x & 63], 1);
    }
    __syncthreads();
    if (t < RPB) {
        int v = cnt[t];
        int s = v;
        for (int off = 1; off < 64; off <<= 1) {
            int u = __shfl_up(s, off, 64);
            if (t >= off) s += u;
        }
        int ex = s - v;               // exclusive
        ofs2[t] = ex;
        rstartL[t] = ex;
        if (t == RPB - 1) rstartL[RPB] = s;   // == n
    }
    __syncthreads();
    // scatter from registers into row-sorted LDS
#pragma unroll
    for (int k = 0; k < 6; ++k) {
        int i = 2 * t + (k >> 1) * 1024 + (k & 1);
        if (i < n) {
            uint2 p = preg[k];
            int rl = p.x & 63;
            int pos = atomicAdd(&ofs2[rl], 1);
            stg[pos] = make_uint2((p.x >> 6) & 0xFFFF, p.y);
        }
    }
    __syncthreads();
    // row phase: 8 waves x 8 rows each; guarded (no break) + unroll 2 for ILP
    int wv = t >> 6;
    int lane = t & 63;
    int sub = lane >> 3;   // edge slot within chunk (0..7)
    int h = lane & 7;      // head
    int r0 = b * RPB;
#pragma unroll 2
    for (int q = 0; q < 8; ++q) {
        int rr = wv * 8 + q;
        int r = r0 + rr;
        if (r < NN) {
            int ls = rstartL[rr];
            int ldeg = rstartL[rr + 1] - ls;
            int tot = ldeg + 1;     // + self loop at slot == ldeg
            float yh = __half2float(ykh[(size_t)r * 16 + 2 * h]);
            float y2s = __half2float(y2h[(size_t)r * 8 + h]);
            float cache[NIT];
            float mx = -__builtin_inff();
#pragma unroll
            for (int it = 0; it < NIT; ++it) {
                int i = it * 8 + sub;
                float a = -__builtin_inff();
                if (i < tot) {
                    if (i < ldeg) {
                        uint2 p = stg[ls + i];
                        a = act((yh + __half2float(y2h[(size_t)p.x * 8 + h])) *
                                __uint_as_float(p.y));
                    } else {
                        a = act(yh + y2s);
                    }
                }
                cache[it] = a;
                mx = fmaxf(mx, a);
            }
            for (int i = NIT * 8 + sub; i < tot; i += 8) {
                float a;
                if (i < ldeg) {
                    uint2 p = stg[ls + i];
                    a = act((yh + __half2float(y2h[(size_t)p.x * 8 + h])) *
                            __uint_as_float(p.y));
                } else {
                    a = act(yh + y2s);
                }
                mx = fmaxf(mx, a);
            }
            mx = fmaxf(mx, __shfl_xor(mx, 8, 64));
            mx = fmaxf(mx, __shfl_xor(mx, 16, 64));
            mx = fmaxf(mx, __shfl_xor(mx, 32, 64));
            float sum = 0.f;
#pragma unroll
            for (int it = 0; it < NIT; ++it)
                sum += __expf(cache[it] - mx);   // exp(-inf)=0 for empty slots
            for (int i = NIT * 8 + sub; i < tot; i += 8) {
                float a;
                if (i < ldeg) {
                    uint2 p = stg[ls + i];
                    a = act((yh + __half2float(y2h[(size_t)p.x * 8 + h])) *
                            __uint_as_float(p.y));
                } else {
                    a = act(yh + y2s);
                }
                sum += __expf(a - mx);
            }
            sum += __shfl_xor(sum, 8, 64);
            sum += __shfl_xor(sum, 16, 64);
            sum += __shfl_xor(sum, 32, 64);
            if (sub == 0) {
                float K = mx + __logf(sum + 1e-16f);
                ykh[(size_t)r * 16 + 2 * h + 1] = __float2half(K);
                float Kr = __half2float(__float2half(K));  // rounded K everywhere
                // self-loop output row e = EE + r
                float os = __expf(act(yh + y2s) - Kr);
                __builtin_nontemporal_store(os, &alpha[(size_t)(EE + r) * 8 + h]);
                if (h == 0) __builtin_nontemporal_store((float)r, &oidx[EE + r]);
                if (h == 1)
                    __builtin_nontemporal_store((float)r,
                                                &oidx[(size_t)TOT + EE + r]);
            }
        }
    }
}

// ---- finalize (e < EE only): 2 heads/thread, single-pass, 4-edge pipeline ----
__global__ __launch_bounds__(256) void k_final(const int* __restrict__ rowp,
                                               const int* __restrict__ colp,
                                               const float* __restrict__ ea,
                                               const __half* __restrict__ ykh,
                                               const __half* __restrict__ y2h,
                                               float* __restrict__ alpha) {
    int gid = blockIdx.x * 256 + threadIdx.x;
    int hp = gid & 3;          // head pair (heads 2hp, 2hp+1)
    int g0 = gid >> 2;
    const int stride = (GRIDF * 256) >> 2;   // edges per step
    for (int e0 = g0; e0 < EE; e0 += UF * stride) {
        int rr[UF], cc[UF]; float ww[UF]; bool hv[UF];
#pragma unroll
        for (int u = 0; u < UF; ++u) {
            int e = e0 + u * stride;
            hv[u] = e < EE;
            rr[u] = 0; cc[u] = 0; ww[u] = 0.f;
            if (hv[u]) {
                rr[u] = rowp[e];
                cc[u] = colp[e];
                ww[u] = fabsf(ea[e]);
            }
        }
        ull yk2[UF]; unsigned v2[UF];
#pragma unroll
        for (int u = 0; u < UF; ++u) {
            yk2[u] = 0ull; v2[u] = 0u;
            if (hv[u]) {
                yk2[u] = *(const ull*)&ykh[(size_t)rr[u] * 16 + 4 * hp];
                v2[u] = *(const unsigned*)&y2h[(size_t)cc[u] * 8 + 2 * hp];
            }
        }
#pragma unroll
        for (int u = 0; u < UF; ++u) {
            if (hv[u]) {
                int e = e0 + u * stride;
                unsigned lo = (unsigned)yk2[u];          // y1b_{2hp}, K_{2hp}
                unsigned hi = (unsigned)(yk2[u] >> 32);  // y1b_{2hp+1}, K_{2hp+1}
                __half2 p0 = *(__half2*)&lo;
                __half2 p1 = *(__half2*)&hi;
                __half2 vvh = *(__half2*)&v2[u];
                float2 f0 = __half22float2(p0);
                float2 f1 = __half22float2(p1);
                float2 vv = __half22float2(vvh);
                float o0 = __expf(act((f0.x + vv.x) * ww[u]) - f0.y);
                float o1 = __expf(act((f1.x + vv.y) * ww[u]) - f1.y);
                ull packed = ((ull)__float_as_uint(o1) << 32) | __float_as_uint(o0);
                __builtin_nontemporal_store(packed,
                    (ull*)&alpha[(size_t)e * 8 + 2 * hp]);
            }
        }
    }
}

extern "C" void kernel_launch(void* const* d_in, const int* in_sizes, int n_in,
                              void* d_out, int out_size, void* d_ws, size_t ws_size,
                              hipStream_t stream) {
    const float* x    = (const float*)d_in[0];
    const int*   rowp = (const int*)d_in[1];          // edge_index[0]
    const int*   colp = rowp + EE;                    // edge_index[1]
    const float* ea   = (const float*)d_in[2];
    const float* W    = (const float*)d_in[3];
    const float* bias = (const float*)d_in[4];

    float* out_alpha = (float*)d_out;                 // [TOT][8]
    float* out_idx   = out_alpha + (size_t)TOT * 8;   // [2][TOT] as float

    // workspace layout
    __half* ykh    = (__half*)d_ws;                   // NN*16 half (y1b|K), 32B/row
    __half* y2h    = ykh + (size_t)NN * 16;           // NN*8 half, 16B/row
    uint2*  pay    = (uint2*)(y2h + (size_t)NN * 8);  // NB*CAP uint2 (16.0 MB)
    int*    gcur0  = (int*)(pay + (size_t)NB * CAP);  // NB (zeroed by k_proj)

    k_proj<<<(NN * 16 + 255) / 256, 256, 0, stream>>>(x, W, bias, ykh, y2h, gcur0);
    k_bin<<<NBB, 1024, 0, stream>>>(rowp, colp, ea, gcur0, pay, out_idx);
    k_sortrow<<<NB, SRT, 0, stream>>>(gcur0, pay, ykh, y2h, out_alpha, out_idx);
    k_final<<<GRIDF, 256, 0, stream>>>(rowp, colp, ea, ykh, y2h, out_alpha);
}